// Round 1
// baseline (400.517 us; speedup 1.0000x reference)
//
#include <hip/hip_runtime.h>
#include <stdint.h>

#define N_NODES 100000
#define N_EDGES 1600000
#define NBLK_SCAN 391   // ceil(N_NODES/256)

typedef __attribute__((ext_vector_type(8))) short short8;
typedef __attribute__((ext_vector_type(4))) float float4v;

__device__ __forceinline__ unsigned short f32_to_bf16(float f) {
  uint32_t u = __float_as_uint(f);
  u += 0x7fffu + ((u >> 16) & 1u);   // RNE
  return (unsigned short)(u >> 16);
}
__device__ __forceinline__ float bf16_to_f32(unsigned short h) {
  return __uint_as_float(((uint32_t)h) << 16);
}

// ---------------------------------------------------------------------------
// K_zero: deg=0; swizzle weight (25 mats -> tiles 0..49) and root_w
// (tiles 50..51) into MFMA B-fragment bf16 order. Also zero the xw pad row
// (col=N-1, w=25 overflow reads) and the ydot pad entry.
// ---------------------------------------------------------------------------
__global__ __launch_bounds__(256) void k_zero(
    const float* __restrict__ weight, const float* __restrict__ root_w,
    int* __restrict__ deg, unsigned short* __restrict__ wbf,
    unsigned short* __restrict__ xw, float* __restrict__ ydot) {
  int tid = threadIdx.x;
  int b = blockIdx.x;
  int i = b * 256 + tid;
  if (i < N_NODES) deg[i] = 0;
  if (b < 100) {            // 25600 weight elements
    int e = i;
    int km = e >> 10;
    int rem = e & 1023;
    int kk = rem >> 5;
    int fo = rem & 31;
    int t = km * 2 + (fo >> 4);
    int c = fo & 15;
    int q = kk >> 3, j = kk & 7;
    wbf[((t * 4 + q) * 16 + c) * 8 + j] = f32_to_bf16(weight[e]);
  } else if (b == 100) {    // 1024 root_w elements -> tiles 50,51
    for (int idx = tid; idx < 1024; idx += 256) {
      int kk = idx >> 5;
      int fo = idx & 31;
      int t = 50 + (fo >> 4);
      int c = fo & 31 & 15;
      int q = kk >> 3, j = kk & 7;
      wbf[((t * 4 + q) * 16 + (fo & 15)) * 8 + j] = f32_to_bf16(root_w[idx]);
      (void)c;
    }
  } else if (b == 101) {    // pads
    if (tid < 400) ((unsigned int*)(xw + 80000000))[tid] = 0u;  // 1600B pad row
    if (tid < 16) ydot[2500000 + tid] = 0.f;
  }
}

// ---------------------------------------------------------------------------
// K1 (6250 blocks, 16 nodes each):
//  - hist: rank[e] = atomicAdd(&deg[ei[e]],1)
//  - xw[n][km*32+fo] bf16 via MFMA 16x16x32 (tiles 0..49), LDS-staged
//  - tiles 50,51 = x @ root_w: out = x_root + bias; r_dot = x_root . att_w[:32]
//  - NEW: ydot[n][km] = sum_f xw[n][km*32+f] * att_w[32+f]  (25 per node)
// ---------------------------------------------------------------------------
__global__ __launch_bounds__(256) void k1_xw(
    const float* __restrict__ x, const unsigned short* __restrict__ wbf,
    const int* __restrict__ ei, const float* __restrict__ att_w,
    const float* __restrict__ bias,
    int* __restrict__ deg, unsigned short* __restrict__ rank,
    unsigned short* __restrict__ xw, float* __restrict__ out,
    float* __restrict__ r_dot, float* __restrict__ ydot) {
  __shared__ __align__(16) unsigned short ot[16 * 808];
  __shared__ float xr[16][33];
  __shared__ float att2s[32];
  int tid = threadIdx.x;
  int b = blockIdx.x;

  if (tid < 32) att2s[tid] = att_w[32 + tid];

  // histogram + rank; store deferred so the atomic overlaps MFMA
  int e = b * 256 + tid;
  int rk = atomicAdd(&deg[ei[e]], 1);

  int wave = tid >> 6, lane = tid & 63;
  int quad = lane >> 4, c16 = lane & 15;
  int n0 = b * 16;
  const float* xp = x + (size_t)(n0 + c16) * 32 + quad * 8;
  float4 a0 = *reinterpret_cast<const float4*>(xp);
  float4 a1 = *reinterpret_cast<const float4*>(xp + 4);
  short8 af;
  af[0] = (short)f32_to_bf16(a0.x); af[1] = (short)f32_to_bf16(a0.y);
  af[2] = (short)f32_to_bf16(a0.z); af[3] = (short)f32_to_bf16(a0.w);
  af[4] = (short)f32_to_bf16(a1.x); af[5] = (short)f32_to_bf16(a1.y);
  af[6] = (short)f32_to_bf16(a1.z); af[7] = (short)f32_to_bf16(a1.w);

  for (int t = wave; t < 52; t += 4) {
    short8 bf = *reinterpret_cast<const short8*>(wbf + ((t * 4 + quad) * 16 + c16) * 8);
    float4v acc = {0.f, 0.f, 0.f, 0.f};
    acc = __builtin_amdgcn_mfma_f32_16x16x32_bf16(af, bf, acc, 0, 0, 0);
    if (t < 50) {
      int cg = t * 16 + c16;
#pragma unroll
      for (int r = 0; r < 4; r++) ot[(quad * 4 + r) * 808 + cg] = f32_to_bf16(acc[r]);
    } else {
      int f = (t - 50) * 16 + c16;
#pragma unroll
      for (int r = 0; r < 4; r++) xr[quad * 4 + r][f] = acc[r];
    }
  }
  __syncthreads();

  // coalesced copy-out: ot rows (101 uint4 stride) -> xw rows (100 uint4)
  const uint4* src = (const uint4*)ot;
  uint4* dst = (uint4*)(xw + (size_t)n0 * 800);
  for (int i = tid; i < 1600; i += 256) {
    int r = i / 100;
    int c = i - r * 100;
    dst[r * 100 + c] = src[r * 101 + c];
  }
  // out = x_root + bias
  for (int idx = tid; idx < 512; idx += 256) {
    int n = idx >> 5, f = idx & 31;
    out[(n0 + n) * 32 + f] = xr[n][f] + bias[f];
  }
  // ydot: 16 nodes x 25 kernels, dot over 32 features (bf16 from LDS)
  for (int idx = tid; idx < 400; idx += 256) {
    int nd = idx / 25;
    int km = idx - nd * 25;
    const unsigned short* orow = ot + nd * 808 + km * 32;
    float s = 0.f;
#pragma unroll
    for (int ff = 0; ff < 32; ff++) s += bf16_to_f32(orow[ff]) * att2s[ff];
    ydot[(size_t)(n0 + nd) * 25 + km] = s;
  }
  // r_dot
  if (tid < 16) {
    float s = 0.f;
#pragma unroll
    for (int f = 0; f < 32; f++) s += xr[tid][f] * att_w[f];
    r_dot[n0 + tid] = s;
  }
  rank[e] = (unsigned short)rk;
}

// ---------------------------------------------------------------------------
// 3-kernel exclusive scan of deg -> offs.
// ---------------------------------------------------------------------------
__global__ __launch_bounds__(256) void kscan1(const int* __restrict__ deg,
                                              int* __restrict__ incl,
                                              int* __restrict__ bsum) {
  __shared__ int s[256];
  int tid = threadIdx.x;
  int i = blockIdx.x * 256 + tid;
  int v = (i < N_NODES) ? deg[i] : 0;
  s[tid] = v;
  __syncthreads();
  for (int d = 1; d < 256; d <<= 1) {
    int t = (tid >= d) ? s[tid - d] : 0;
    __syncthreads();
    s[tid] += t;
    __syncthreads();
  }
  if (i < N_NODES) incl[i] = s[tid];
  if (tid == 255) bsum[blockIdx.x] = s[255];
}

__global__ __launch_bounds__(512) void kscan2(const int* __restrict__ bsum,
                                              int* __restrict__ bbase) {
  __shared__ int s[512];
  int tid = threadIdx.x;
  int v = (tid < NBLK_SCAN) ? bsum[tid] : 0;
  s[tid] = v;
  __syncthreads();
  for (int d = 1; d < 512; d <<= 1) {
    int t = (tid >= d) ? s[tid - d] : 0;
    __syncthreads();
    s[tid] += t;
    __syncthreads();
  }
  if (tid < NBLK_SCAN) bbase[tid] = s[tid] - v;  // exclusive
}

__global__ __launch_bounds__(256) void kscan3(const int* __restrict__ deg,
                                              int* __restrict__ offs,
                                              const int* __restrict__ bbase) {
  int i = blockIdx.x * 256 + threadIdx.x;
  if (i < N_NODES) offs[i] = offs[i] - deg[i] + bbase[i >> 8];
  if (i == 0) offs[N_NODES] = N_EDGES;
}

// ---------------------------------------------------------------------------
// K_scatter: NO atomics — pos = offs[row] + rank[e].
// NEW: computes alpha = r_dot[row] + interp(ydot[col]) with FULL-precision fr,
// applies leaky-relu + exp ONCE PER EDGE, and stores per-edge payload:
//   eidx[pos]  = col(17b) | w0(5b) | w2(5b)     (w1=w0+1, w3=w2+1; clamp
//                cases have zero coefficient so the +1 row read is harmless)
//   ecoef[pos] = { bf16(b0*ex)|bf16(b1*ex)<<16, bf16(b2*ex)|bf16(b3*ex)<<16 }
// Note sum of coefs == ex, so k2 recovers the softmax denominator for free.
// ---------------------------------------------------------------------------
__global__ __launch_bounds__(256) void kscatter(
    const int* __restrict__ ei, const float* __restrict__ pseudo,
    const int* __restrict__ offs, const unsigned short* __restrict__ rank,
    const float* __restrict__ ydot, const float* __restrict__ r_dot,
    unsigned int* __restrict__ eidx, uint2* __restrict__ ecoef) {
  int tid = threadIdx.x;
  int base = blockIdx.x * 2048;
#pragma unroll
  for (int k = 0; k < 8; k++) {
    int e = base + k * 256 + tid;
    if (e < N_EDGES) {
      int r = ei[e];
      int c = ei[N_EDGES + e];
      int pos = offs[r] + (int)rank[e];
      float p0 = pseudo[2 * e] * 4.f;
      float p1 = pseudo[2 * e + 1] * 4.f;
      float fl0 = floorf(p0), fl1 = floorf(p1);
      float fr0 = p0 - fl0, fr1 = p1 - fl1;
      int i0 = (int)fl0, i1 = (int)fl1;
      int w0 = min(i0, 4) + 5 * min(i1, 4);
      int w2 = min(i0, 4) + 5 * min(i1 + 1, 4);
      const float* yb = ydot + (size_t)c * 25;
      float y0 = yb[w0], y1 = yb[w0 + 1];
      float y2 = yb[w2], y3 = yb[w2 + 1];
      float c0 = 1.f - fr0, c1 = 1.f - fr1;
      float b0 = c0 * c1, b1 = fr0 * c1, b2 = c0 * fr1, b3 = fr0 * fr1;
      float alpha = r_dot[r] + b0 * y0 + b1 * y1 + b2 * y2 + b3 * y3;
      alpha = alpha > 0.f ? alpha : 0.2f * alpha;
      float ex = __expf(alpha);
      unsigned int q01 = (unsigned int)f32_to_bf16(b0 * ex) |
                         ((unsigned int)f32_to_bf16(b1 * ex) << 16);
      unsigned int q23 = (unsigned int)f32_to_bf16(b2 * ex) |
                         ((unsigned int)f32_to_bf16(b3 * ex) << 16);
      uint2 pk;
      pk.x = q01;
      pk.y = q23;
      ecoef[pos] = pk;
      eidx[pos] = (unsigned int)c | ((unsigned int)w0 << 17) |
                  ((unsigned int)w2 << 22);
    }
  }
}

// ---------------------------------------------------------------------------
// K2: one wave per node; halves process alternate edges (lane=f_out);
// 4-deep unroll per half. Slim loop: NO shuffle reduction, NO exp —
// acc += sum_s q_s * g_s (== msg*ex), den += sum_s q_s (== ex).
// ---------------------------------------------------------------------------
__global__ __launch_bounds__(256) void k2_csr(
    const int* __restrict__ offs, const unsigned int* __restrict__ eidx,
    const uint2* __restrict__ ecoef, const unsigned short* __restrict__ xw,
    float* __restrict__ out) {
  int tid = threadIdx.x;
  int wave = tid >> 6, lane = tid & 63;
  int node = blockIdx.x * 4 + wave;
  if (node >= N_NODES) return;
  int f = lane & 31, half = lane >> 5;
  int s0 = offs[node], s1 = offs[node + 1];
  const unsigned short* xwf = xw + f;
  float accA = 0.f, accB = 0.f, denA = 0.f, denB = 0.f;
  int i = s0 + half;

  for (; i + 6 < s1; i += 8) {
    unsigned int id[4];
    uint2 cf[4];
    id[0] = eidx[i];     id[1] = eidx[i + 2];
    id[2] = eidx[i + 4]; id[3] = eidx[i + 6];
    cf[0] = ecoef[i];     cf[1] = ecoef[i + 2];
    cf[2] = ecoef[i + 4]; cf[3] = ecoef[i + 6];
    float g0[4], g1[4], g2[4], g3[4];
#pragma unroll
    for (int u = 0; u < 4; u++) {
      const unsigned short* base = xwf + (size_t)(id[u] & 0x1FFFF) * 800;
      int o0 = ((id[u] >> 17) & 31) * 32;
      int o2 = ((id[u] >> 22) & 31) * 32;
      g0[u] = bf16_to_f32(base[o0]);
      g1[u] = bf16_to_f32(base[o0 + 32]);
      g2[u] = bf16_to_f32(base[o2]);
      g3[u] = bf16_to_f32(base[o2 + 32]);
    }
#pragma unroll
    for (int u = 0; u < 4; u++) {
      float q0 = __uint_as_float(cf[u].x << 16);
      float q1 = __uint_as_float(cf[u].x & 0xffff0000u);
      float q2 = __uint_as_float(cf[u].y << 16);
      float q3 = __uint_as_float(cf[u].y & 0xffff0000u);
      float m = q0 * g0[u] + q1 * g1[u] + q2 * g2[u] + q3 * g3[u];
      float d = (q0 + q1) + (q2 + q3);
      if (u & 1) { accB += m; denB += d; } else { accA += m; denA += d; }
    }
  }
  for (; i < s1; i += 2) {
    unsigned int idv = eidx[i];
    uint2 cfv = ecoef[i];
    const unsigned short* base = xwf + (size_t)(idv & 0x1FFFF) * 800;
    int o0 = ((idv >> 17) & 31) * 32;
    int o2 = ((idv >> 22) & 31) * 32;
    float g0 = bf16_to_f32(base[o0]);
    float g1 = bf16_to_f32(base[o0 + 32]);
    float g2 = bf16_to_f32(base[o2]);
    float g3 = bf16_to_f32(base[o2 + 32]);
    float q0 = __uint_as_float(cfv.x << 16);
    float q1 = __uint_as_float(cfv.x & 0xffff0000u);
    float q2 = __uint_as_float(cfv.y << 16);
    float q3 = __uint_as_float(cfv.y & 0xffff0000u);
    accA += q0 * g0 + q1 * g1 + q2 * g2 + q3 * g3;
    denA += (q0 + q1) + (q2 + q3);
  }

  float acc = accA + accB;
  float den = denA + denB;
  acc += __shfl_xor(acc, 32);
  den += __shfl_xor(den, 32);
  if (half == 0) out[node * 32 + f] += acc / (den + 1e-16f);
}

extern "C" void kernel_launch(void* const* d_in, const int* in_sizes, int n_in,
                              void* d_out, int out_size, void* d_ws, size_t ws_size,
                              hipStream_t stream) {
  const float* x      = (const float*)d_in[0];
  const int*   ei     = (const int*)d_in[1];
  const float* pseudo = (const float*)d_in[2];
  const float* weight = (const float*)d_in[3];
  const float* root_w = (const float*)d_in[4];
  const float* att_w  = (const float*)d_in[5];
  const float* bias   = (const float*)d_in[6];
  float* out = (float*)d_out;

  char* ws = (char*)d_ws;
  unsigned short* xw   = (unsigned short*)ws;                 // 160,001,600 B (incl. 1600B pad row)
  float* ydot          = (float*)(ws + 160001600);            //  10,000,064 B (2.5M + pad)
  float* r_dot         = (float*)(ws + 170001664);            //     400,000 B
  unsigned short* wbf  = (unsigned short*)(ws + 170401664);   //      53,248 B
  int* deg             = (int*)(ws + 170454912);              //     400,000 B
  int* offs            = (int*)(ws + 170854912);              //     400,064 B
  int* bsum            = (int*)(ws + 171254976);              //       1,600 B
  int* bbase           = (int*)(ws + 171256576);              //       1,600 B
  unsigned short* rank = (unsigned short*)(ws + 171258176);   //   3,200,000 B
  uint2* ecoef         = (uint2*)(ws + 174458176);            //  12,800,000 B
  unsigned int* eidx   = (unsigned int*)(ws + 187258176);     //   6,400,000 B -> 193.66 MB

  hipLaunchKernelGGL(k_zero, dim3(NBLK_SCAN), dim3(256), 0, stream,
                     weight, root_w, deg, wbf, xw, ydot);
  hipLaunchKernelGGL(k1_xw, dim3(6250), dim3(256), 0, stream,
                     x, wbf, ei, att_w, bias, deg, rank, xw, out, r_dot, ydot);
  hipLaunchKernelGGL(kscan1, dim3(NBLK_SCAN), dim3(256), 0, stream, deg, offs, bsum);
  hipLaunchKernelGGL(kscan2, dim3(1), dim3(512), 0, stream, bsum, bbase);
  hipLaunchKernelGGL(kscan3, dim3(NBLK_SCAN), dim3(256), 0, stream, deg, offs, bbase);
  hipLaunchKernelGGL(kscatter, dim3(782), dim3(256), 0, stream,
                     ei, pseudo, offs, rank, ydot, r_dot, eidx, ecoef);
  hipLaunchKernelGGL(k2_csr, dim3(25000), dim3(256), 0, stream,
                     offs, eidx, ecoef, xw, out);
}

// Round 2
// 378.068 us; speedup vs baseline: 1.0594x; 1.0594x over previous
//
#include <hip/hip_runtime.h>
#include <stdint.h>

#define N_NODES 100000
#define N_EDGES 1600000
#define NBLK_SCAN 391   // ceil(N_NODES/256)

typedef __attribute__((ext_vector_type(8))) short short8;
typedef __attribute__((ext_vector_type(4))) float float4v;

__device__ __forceinline__ unsigned short f32_to_bf16(float f) {
  uint32_t u = __float_as_uint(f);
  u += 0x7fffu + ((u >> 16) & 1u);   // RNE
  return (unsigned short)(u >> 16);
}
__device__ __forceinline__ float bf16_to_f32(unsigned short h) {
  return __uint_as_float(((uint32_t)h) << 16);
}

// ---------------------------------------------------------------------------
// K_zero: deg=0; swizzle weight (25 mats -> tiles 0..49) and root_w
// (tiles 50..51) into MFMA B-fragment bf16 order. Also zero the xw pad row
// (col=N-1, w=25 overflow reads) and the ydot pad entry.
// ---------------------------------------------------------------------------
__global__ __launch_bounds__(256) void k_zero(
    const float* __restrict__ weight, const float* __restrict__ root_w,
    int* __restrict__ deg, unsigned short* __restrict__ wbf,
    unsigned short* __restrict__ xw, float* __restrict__ ydot) {
  int tid = threadIdx.x;
  int b = blockIdx.x;
  int i = b * 256 + tid;
  if (i < N_NODES) deg[i] = 0;
  if (b < 100) {            // 25600 weight elements
    int e = i;
    int km = e >> 10;
    int rem = e & 1023;
    int kk = rem >> 5;
    int fo = rem & 31;
    int t = km * 2 + (fo >> 4);
    int c = fo & 15;
    int q = kk >> 3, j = kk & 7;
    wbf[((t * 4 + q) * 16 + c) * 8 + j] = f32_to_bf16(weight[e]);
  } else if (b == 100) {    // 1024 root_w elements -> tiles 50,51
    for (int idx = tid; idx < 1024; idx += 256) {
      int kk = idx >> 5;
      int fo = idx & 31;
      int t = 50 + (fo >> 4);
      int q = kk >> 3, j = kk & 7;
      wbf[((t * 4 + q) * 16 + (fo & 15)) * 8 + j] = f32_to_bf16(root_w[idx]);
    }
  } else if (b == 101) {    // pads
    if (tid < 400) ((unsigned int*)(xw + 80000000))[tid] = 0u;  // 1600B pad row
    if (tid < 16) ydot[2500000 + tid] = 0.f;
  }
}

// ---------------------------------------------------------------------------
// K1 (6250 blocks, 16 nodes each):
//  - hist: rank[e] = atomicAdd(&deg[ei[e]],1)
//  - xw[n][km*32+fo] bf16 via MFMA 16x16x32 (tiles 0..49), LDS-staged
//  - tiles 50,51 = x @ root_w: out = x_root + bias; od[n].y = x_root.att_w[:32]
//  - ydot[n][km] = sum_f xw[n][km*32+f] * att_w[32+f]  (25 per node)
// ---------------------------------------------------------------------------
__global__ __launch_bounds__(256) void k1_xw(
    const float* __restrict__ x, const unsigned short* __restrict__ wbf,
    const int* __restrict__ ei, const float* __restrict__ att_w,
    const float* __restrict__ bias,
    int* __restrict__ deg, unsigned short* __restrict__ rank,
    unsigned short* __restrict__ xw, float* __restrict__ out,
    uint2* __restrict__ od, float* __restrict__ ydot) {
  __shared__ __align__(16) unsigned short ot[16 * 808];
  __shared__ float xr[16][33];
  __shared__ float att2s[32];
  int tid = threadIdx.x;
  int b = blockIdx.x;

  if (tid < 32) att2s[tid] = att_w[32 + tid];

  // histogram + rank; store deferred so the atomic overlaps MFMA
  int e = b * 256 + tid;
  int rk = atomicAdd(&deg[ei[e]], 1);

  int wave = tid >> 6, lane = tid & 63;
  int quad = lane >> 4, c16 = lane & 15;
  int n0 = b * 16;
  const float* xp = x + (size_t)(n0 + c16) * 32 + quad * 8;
  float4 a0 = *reinterpret_cast<const float4*>(xp);
  float4 a1 = *reinterpret_cast<const float4*>(xp + 4);
  short8 af;
  af[0] = (short)f32_to_bf16(a0.x); af[1] = (short)f32_to_bf16(a0.y);
  af[2] = (short)f32_to_bf16(a0.z); af[3] = (short)f32_to_bf16(a0.w);
  af[4] = (short)f32_to_bf16(a1.x); af[5] = (short)f32_to_bf16(a1.y);
  af[6] = (short)f32_to_bf16(a1.z); af[7] = (short)f32_to_bf16(a1.w);

  for (int t = wave; t < 52; t += 4) {
    short8 bf = *reinterpret_cast<const short8*>(wbf + ((t * 4 + quad) * 16 + c16) * 8);
    float4v acc = {0.f, 0.f, 0.f, 0.f};
    acc = __builtin_amdgcn_mfma_f32_16x16x32_bf16(af, bf, acc, 0, 0, 0);
    if (t < 50) {
      int cg = t * 16 + c16;
#pragma unroll
      for (int r = 0; r < 4; r++) ot[(quad * 4 + r) * 808 + cg] = f32_to_bf16(acc[r]);
    } else {
      int f = (t - 50) * 16 + c16;
#pragma unroll
      for (int r = 0; r < 4; r++) xr[quad * 4 + r][f] = acc[r];
    }
  }
  __syncthreads();

  // coalesced copy-out: ot rows (101 uint4 stride) -> xw rows (100 uint4)
  const uint4* src = (const uint4*)ot;
  uint4* dst = (uint4*)(xw + (size_t)n0 * 800);
  for (int i = tid; i < 1600; i += 256) {
    int r = i / 100;
    int c = i - r * 100;
    dst[r * 100 + c] = src[r * 101 + c];
  }
  // out = x_root + bias
  for (int idx = tid; idx < 512; idx += 256) {
    int n = idx >> 5, f = idx & 31;
    out[(n0 + n) * 32 + f] = xr[n][f] + bias[f];
  }
  // ydot: 16 nodes x 25 kernels, dot over 32 features (bf16 from LDS)
  for (int idx = tid; idx < 400; idx += 256) {
    int nd = idx / 25;
    int km = idx - nd * 25;
    const unsigned short* orow = ot + nd * 808 + km * 32;
    float s = 0.f;
#pragma unroll
    for (int ff = 0; ff < 32; ff++) s += bf16_to_f32(orow[ff]) * att2s[ff];
    ydot[(size_t)(n0 + nd) * 25 + km] = s;
  }
  // r_dot -> od[].y (packed with offs in .x, written later by kscan3)
  if (tid < 16) {
    float s = 0.f;
#pragma unroll
    for (int f = 0; f < 32; f++) s += xr[tid][f] * att_w[f];
    od[n0 + tid].y = __float_as_uint(s);
  }
  rank[e] = (unsigned short)rk;
}

// ---------------------------------------------------------------------------
// 3-kernel exclusive scan of deg -> offs.
// ---------------------------------------------------------------------------
__global__ __launch_bounds__(256) void kscan1(const int* __restrict__ deg,
                                              int* __restrict__ incl,
                                              int* __restrict__ bsum) {
  __shared__ int s[256];
  int tid = threadIdx.x;
  int i = blockIdx.x * 256 + tid;
  int v = (i < N_NODES) ? deg[i] : 0;
  s[tid] = v;
  __syncthreads();
  for (int d = 1; d < 256; d <<= 1) {
    int t = (tid >= d) ? s[tid - d] : 0;
    __syncthreads();
    s[tid] += t;
    __syncthreads();
  }
  if (i < N_NODES) incl[i] = s[tid];
  if (tid == 255) bsum[blockIdx.x] = s[255];
}

__global__ __launch_bounds__(512) void kscan2(const int* __restrict__ bsum,
                                              int* __restrict__ bbase) {
  __shared__ int s[512];
  int tid = threadIdx.x;
  int v = (tid < NBLK_SCAN) ? bsum[tid] : 0;
  s[tid] = v;
  __syncthreads();
  for (int d = 1; d < 512; d <<= 1) {
    int t = (tid >= d) ? s[tid - d] : 0;
    __syncthreads();
    s[tid] += t;
    __syncthreads();
  }
  if (tid < NBLK_SCAN) bbase[tid] = s[tid] - v;  // exclusive
}

__global__ __launch_bounds__(256) void kscan3(const int* __restrict__ deg,
                                              int* __restrict__ offs,
                                              const int* __restrict__ bbase,
                                              uint2* __restrict__ od) {
  int i = blockIdx.x * 256 + threadIdx.x;
  if (i < N_NODES) {
    int v = offs[i] - deg[i] + bbase[i >> 8];
    offs[i] = v;
    od[i].x = (unsigned int)v;   // pack exclusive offset next to r_dot bits
  }
  if (i == 0) offs[N_NODES] = N_EDGES;
}

// ---------------------------------------------------------------------------
// K_scatter: 1 edge/thread, 6250 blocks (25000 waves -> full device; the
// round-1 version at 782 blocks was latency-bound: VALUBusy 2.3%, occ 24%).
// pos = od[row].x + rank[e]; alpha from ydot[col] gather + od[row].y (r_dot).
//   eidx[pos]  = col(17b) | w0(5b) | w2(5b)
//   ecoef[pos] = { bf16(b0*ex)|bf16(b1*ex)<<16, bf16(b2*ex)|bf16(b3*ex)<<16 }
// Sum of coefs == ex, so k2 recovers the softmax denominator for free.
// ---------------------------------------------------------------------------
__global__ __launch_bounds__(256) void kscatter(
    const int* __restrict__ ei, const float* __restrict__ pseudo,
    const uint2* __restrict__ od, const unsigned short* __restrict__ rank,
    const float* __restrict__ ydot,
    unsigned int* __restrict__ eidx, uint2* __restrict__ ecoef) {
  int e = blockIdx.x * 256 + threadIdx.x;
  // independent coalesced loads first
  int r = ei[e];
  int c = ei[N_EDGES + e];
  float p0 = pseudo[2 * e] * 4.f;
  float p1 = pseudo[2 * e + 1] * 4.f;
  int rk = rank[e];
  // one random line for the row side (offs + r_dot packed)
  uint2 v = od[r];
  float fl0 = floorf(p0), fl1 = floorf(p1);
  float fr0 = p0 - fl0, fr1 = p1 - fl1;
  int i0 = (int)fl0, i1 = (int)fl1;
  int w0 = min(i0, 4) + 5 * min(i1, 4);
  int w2 = min(i0, 4) + 5 * min(i1 + 1, 4);
  // random gather of 4 ydot values (one 100B row, 1-2 lines)
  const float* yb = ydot + (size_t)c * 25;
  float y0 = yb[w0], y1 = yb[w0 + 1];
  float y2 = yb[w2], y3 = yb[w2 + 1];
  float c0 = 1.f - fr0, c1 = 1.f - fr1;
  float b0 = c0 * c1, b1 = fr0 * c1, b2 = c0 * fr1, b3 = fr0 * fr1;
  float alpha = __uint_as_float(v.y) + b0 * y0 + b1 * y1 + b2 * y2 + b3 * y3;
  alpha = alpha > 0.f ? alpha : 0.2f * alpha;
  float ex = __expf(alpha);
  int pos = (int)v.x + rk;
  uint2 pk;
  pk.x = (unsigned int)f32_to_bf16(b0 * ex) |
         ((unsigned int)f32_to_bf16(b1 * ex) << 16);
  pk.y = (unsigned int)f32_to_bf16(b2 * ex) |
         ((unsigned int)f32_to_bf16(b3 * ex) << 16);
  ecoef[pos] = pk;
  eidx[pos] = (unsigned int)c | ((unsigned int)w0 << 17) |
              ((unsigned int)w2 << 22);
}

// ---------------------------------------------------------------------------
// K2: one wave per node; halves process alternate edges (lane=f_out);
// 4-deep unroll per half. Slim loop: NO shuffle reduction, NO exp —
// acc += sum_s q_s * g_s (== msg*ex), den += sum_s q_s (== ex).
// ---------------------------------------------------------------------------
__global__ __launch_bounds__(256) void k2_csr(
    const int* __restrict__ offs, const unsigned int* __restrict__ eidx,
    const uint2* __restrict__ ecoef, const unsigned short* __restrict__ xw,
    float* __restrict__ out) {
  int tid = threadIdx.x;
  int wave = tid >> 6, lane = tid & 63;
  int node = blockIdx.x * 4 + wave;
  if (node >= N_NODES) return;
  int f = lane & 31, half = lane >> 5;
  int s0 = offs[node], s1 = offs[node + 1];
  const unsigned short* xwf = xw + f;
  float accA = 0.f, accB = 0.f, denA = 0.f, denB = 0.f;
  int i = s0 + half;

  for (; i + 6 < s1; i += 8) {
    unsigned int id[4];
    uint2 cf[4];
    id[0] = eidx[i];     id[1] = eidx[i + 2];
    id[2] = eidx[i + 4]; id[3] = eidx[i + 6];
    cf[0] = ecoef[i];     cf[1] = ecoef[i + 2];
    cf[2] = ecoef[i + 4]; cf[3] = ecoef[i + 6];
    float g0[4], g1[4], g2[4], g3[4];
#pragma unroll
    for (int u = 0; u < 4; u++) {
      const unsigned short* base = xwf + (size_t)(id[u] & 0x1FFFF) * 800;
      int o0 = ((id[u] >> 17) & 31) * 32;
      int o2 = ((id[u] >> 22) & 31) * 32;
      g0[u] = bf16_to_f32(base[o0]);
      g1[u] = bf16_to_f32(base[o0 + 32]);
      g2[u] = bf16_to_f32(base[o2]);
      g3[u] = bf16_to_f32(base[o2 + 32]);
    }
#pragma unroll
    for (int u = 0; u < 4; u++) {
      float q0 = __uint_as_float(cf[u].x << 16);
      float q1 = __uint_as_float(cf[u].x & 0xffff0000u);
      float q2 = __uint_as_float(cf[u].y << 16);
      float q3 = __uint_as_float(cf[u].y & 0xffff0000u);
      float m = q0 * g0[u] + q1 * g1[u] + q2 * g2[u] + q3 * g3[u];
      float d = (q0 + q1) + (q2 + q3);
      if (u & 1) { accB += m; denB += d; } else { accA += m; denA += d; }
    }
  }
  for (; i < s1; i += 2) {
    unsigned int idv = eidx[i];
    uint2 cfv = ecoef[i];
    const unsigned short* base = xwf + (size_t)(idv & 0x1FFFF) * 800;
    int o0 = ((idv >> 17) & 31) * 32;
    int o2 = ((idv >> 22) & 31) * 32;
    float g0 = bf16_to_f32(base[o0]);
    float g1 = bf16_to_f32(base[o0 + 32]);
    float g2 = bf16_to_f32(base[o2]);
    float g3 = bf16_to_f32(base[o2 + 32]);
    float q0 = __uint_as_float(cfv.x << 16);
    float q1 = __uint_as_float(cfv.x & 0xffff0000u);
    float q2 = __uint_as_float(cfv.y << 16);
    float q3 = __uint_as_float(cfv.y & 0xffff0000u);
    accA += q0 * g0 + q1 * g1 + q2 * g2 + q3 * g3;
    denA += (q0 + q1) + (q2 + q3);
  }

  float acc = accA + accB;
  float den = denA + denB;
  acc += __shfl_xor(acc, 32);
  den += __shfl_xor(den, 32);
  if (half == 0) out[node * 32 + f] += acc / (den + 1e-16f);
}

extern "C" void kernel_launch(void* const* d_in, const int* in_sizes, int n_in,
                              void* d_out, int out_size, void* d_ws, size_t ws_size,
                              hipStream_t stream) {
  const float* x      = (const float*)d_in[0];
  const int*   ei     = (const int*)d_in[1];
  const float* pseudo = (const float*)d_in[2];
  const float* weight = (const float*)d_in[3];
  const float* root_w = (const float*)d_in[4];
  const float* att_w  = (const float*)d_in[5];
  const float* bias   = (const float*)d_in[6];
  float* out = (float*)d_out;

  char* ws = (char*)d_ws;
  unsigned short* xw   = (unsigned short*)ws;                 // 160,001,600 B (incl. 1600B pad row)
  float* ydot          = (float*)(ws + 160001600);            //  10,000,064 B (2.5M + pad)
  uint2* od            = (uint2*)(ws + 170001664);            //     800,000 B {offs, r_dot bits}
  unsigned short* wbf  = (unsigned short*)(ws + 170801664);   //      53,248 B
  int* deg             = (int*)(ws + 170854912);              //     400,000 B
  int* offs            = (int*)(ws + 171254912);              //     400,016 B
  int* bsum            = (int*)(ws + 171654928);              //       1,600 B
  int* bbase           = (int*)(ws + 171656528);              //       1,600 B
  unsigned short* rank = (unsigned short*)(ws + 171658128);   //   3,200,000 B
  uint2* ecoef         = (uint2*)(ws + 174858128);            //  12,800,000 B
  unsigned int* eidx   = (unsigned int*)(ws + 187658128);     //   6,400,000 B -> 194.06 MB

  hipLaunchKernelGGL(k_zero, dim3(NBLK_SCAN), dim3(256), 0, stream,
                     weight, root_w, deg, wbf, xw, ydot);
  hipLaunchKernelGGL(k1_xw, dim3(6250), dim3(256), 0, stream,
                     x, wbf, ei, att_w, bias, deg, rank, xw, out, od, ydot);
  hipLaunchKernelGGL(kscan1, dim3(NBLK_SCAN), dim3(256), 0, stream, deg, offs, bsum);
  hipLaunchKernelGGL(kscan2, dim3(1), dim3(512), 0, stream, bsum, bbase);
  hipLaunchKernelGGL(kscan3, dim3(NBLK_SCAN), dim3(256), 0, stream, deg, offs, bbase, od);
  hipLaunchKernelGGL(kscatter, dim3(6250), dim3(256), 0, stream,
                     ei, pseudo, od, rank, ydot, eidx, ecoef);
  hipLaunchKernelGGL(k2_csr, dim3(25000), dim3(256), 0, stream,
                     offs, eidx, ecoef, xw, out);
}